// Round 7
// baseline (512.023 us; speedup 1.0000x reference)
//
#include <hip/hip_runtime.h>

#define D_SZ 768
#define N_SZ 50000
#define L_SZ 28
#define B_SZ 1024
#define NP   50048   // 391 * 128 (padded N)
#define NT   391     // n-tiles of 128

typedef __bf16 bf16x8 __attribute__((ext_vector_type(8)));
typedef float f32x4 __attribute__((ext_vector_type(4)));
typedef unsigned short u16x8 __attribute__((ext_vector_type(8)));

__device__ __forceinline__ unsigned short f2bf(float f) {
  union { float f; unsigned u; } v; v.f = f;
  unsigned r = v.u + 0x7FFFu + ((v.u >> 16) & 1u);
  return (unsigned short)(r >> 16);
}
__device__ __forceinline__ unsigned cvt_pk_bf16(float lo, float hi) {
  unsigned r;
  asm("v_cvt_pk_bf16_f32 %0, %1, %2" : "=v"(r) : "v"(lo), "v"(hi));
  return r;
}

// ---------------------------------------------------------------------------
// Streaming f32 -> bf16 convert, 8 elems/thread.
// ---------------------------------------------------------------------------
__global__ void conv8(const float* __restrict__ in, unsigned short* __restrict__ out, int n8)
{
  const int t = blockIdx.x * 256 + threadIdx.x;
  if (t >= n8) return;
  const float4 a0 = *(const float4*)(in + (size_t)t * 8);
  const float4 a1 = *(const float4*)(in + (size_t)t * 8 + 4);
  uint4 o;
  o.x = cvt_pk_bf16(a0.x, a0.y);
  o.y = cvt_pk_bf16(a0.z, a0.w);
  o.z = cvt_pk_bf16(a1.x, a1.y);
  o.w = cvt_pk_bf16(a1.z, a1.w);
  *(uint4*)(out + (size_t)t * 8) = o;
}

// ---------------------------------------------------------------------------
// Projection GEMM: Y[M][768] bf16 = X @ W^T. 128x128 tile, BK=32, 4 waves.
// 2-phase dbuf: stage K-step k+1 BEFORE computing k (load latency overlaps
// ds_read+MFMA instead of preceding it). Co-XCD id swizzle.
// ---------------------------------------------------------------------------
__global__ __launch_bounds__(256, 2)
void proj_gemm2(const unsigned short* __restrict__ Xfb,
                const unsigned short* __restrict__ Xeb,
                const float* __restrict__ Xef,
                const unsigned short* __restrict__ Wb,
                unsigned short* __restrict__ Yf, unsigned short* __restrict__ Ye,
                float* __restrict__ ssqF, float* __restrict__ ssqE,
                int exBf)
{
  const int id = blockIdx.x;
  const int slot = id & 7, rest = id >> 3;
  const int x = rest % 6, yq = rest / 6;
  const int y = yq * 8 + slot;
  if (y >= 8 + NT) return;

  __shared__ __align__(16) unsigned short As[2][128 * 32];
  __shared__ __align__(16) unsigned short Bs[2][128 * 32];
  const int tid = threadIdx.x;
  const int w = tid >> 6, lane = tid & 63;
  const int wr = w >> 1, wc = w & 1;
  const int fr = lane & 15, fq = lane >> 4;
  const int fk = fq << 3;
  const int srow = lane >> 2;
  const int scol = (lane & 3) << 3;
  const int o0 = x * 128;

  const unsigned short* Xb; const float* Xf32; unsigned short* Y;
  float* ssqG; int m0, Mvalid; bool abf;
  if (y < 8) { Xb = Xfb; Xf32 = nullptr; Y = Yf; ssqG = ssqF; m0 = y * 128; Mvalid = B_SZ; abf = true; }
  else { Xb = Xeb; Xf32 = Xef; Y = Ye; ssqG = ssqE; m0 = (y - 8) * 128; Mvalid = N_SZ; abf = (exBf != 0); }

  auto stage = [&](int buf, int kk) {
    if (abf) {
#pragma unroll
      for (int i = 0; i < 2; ++i) {
        const int chunk = w * 2 + i;
        const int row = chunk * 16 + srow;
        const unsigned short* ga = Xb + (size_t)(m0 + row) * D_SZ + kk + scol;
        __builtin_amdgcn_global_load_lds((const __attribute__((address_space(1))) void*)ga,
                                         (__attribute__((address_space(3))) void*)&As[buf][chunk * 512],
                                         16, 0, 0);
      }
    } else {
#pragma unroll
      for (int i = 0; i < 2; ++i) {
        const int idx = tid + i * 256;
        const int row = idx >> 2;
        const int c8 = (idx & 3) << 3;
        float4 a0, a1;
        if (m0 + row < Mvalid) {
          const float* p = Xf32 + (size_t)(m0 + row) * D_SZ + kk + c8;
          a0 = *(const float4*)p; a1 = *(const float4*)(p + 4);
        } else { a0 = make_float4(0.f, 0.f, 0.f, 0.f); a1 = a0; }
        u16x8 av;
        av[0] = f2bf(a0.x); av[1] = f2bf(a0.y); av[2] = f2bf(a0.z); av[3] = f2bf(a0.w);
        av[4] = f2bf(a1.x); av[5] = f2bf(a1.y); av[6] = f2bf(a1.z); av[7] = f2bf(a1.w);
        *(u16x8*)&As[buf][row * 32 + c8] = av;
      }
    }
#pragma unroll
    for (int i = 0; i < 2; ++i) {
      const int chunk = w * 2 + i;
      const int row = chunk * 16 + srow;
      const unsigned short* gb = Wb + (size_t)(o0 + row) * D_SZ + kk + scol;
      __builtin_amdgcn_global_load_lds((const __attribute__((address_space(1))) void*)gb,
                                       (__attribute__((address_space(3))) void*)&Bs[buf][chunk * 512],
                                       16, 0, 0);
    }
  };

  f32x4 acc[4][4] = {};
  int cur = 0;
  stage(0, 0);
  __syncthreads();

  for (int kk = 0; kk < D_SZ; kk += 32) {
    if (kk + 32 < D_SZ) stage(cur ^ 1, kk + 32);
    bf16x8 af[4], bfv[4];
#pragma unroll
    for (int i = 0; i < 4; ++i) {
      af[i]  = *(const bf16x8*)&As[cur][(wr * 64 + i * 16 + fr) * 32 + fk];
      bfv[i] = *(const bf16x8*)&Bs[cur][(wc * 64 + i * 16 + fr) * 32 + fk];
    }
#pragma unroll
    for (int mi = 0; mi < 4; ++mi)
#pragma unroll
      for (int ni = 0; ni < 4; ++ni)
        acc[mi][ni] = __builtin_amdgcn_mfma_f32_16x16x32_bf16(af[mi], bfv[ni], acc[mi][ni], 0, 0, 0);
    __syncthreads();
    cur ^= 1;
  }

  float ssq[4][4] = {};
#pragma unroll
  for (int mi = 0; mi < 4; ++mi)
#pragma unroll
    for (int ni = 0; ni < 4; ++ni)
#pragma unroll
      for (int r = 0; r < 4; ++r) {
        const int row = m0 + wr * 64 + mi * 16 + fq * 4 + r;
        const int col = o0 + wc * 64 + ni * 16 + fr;
        const float v = acc[mi][ni][r];
        Y[(size_t)row * D_SZ + col] = f2bf(v);
        ssq[mi][r] += v * v;
      }
#pragma unroll
  for (int mi = 0; mi < 4; ++mi)
#pragma unroll
    for (int r = 0; r < 4; ++r) {
      float v = ssq[mi][r];
      v += __shfl_xor(v, 1); v += __shfl_xor(v, 2);
      v += __shfl_xor(v, 4); v += __shfl_xor(v, 8);
      if (fr == 0) atomicAdd(&ssqG[m0 + wr * 64 + mi * 16 + fq * 4 + r], v);
    }
}

// ---------------------------------------------------------------------------
// Build excT bf16 [32][NP] + fused per-class counts.
// ---------------------------------------------------------------------------
__global__ void excT_prep(const float* __restrict__ exc, unsigned short* __restrict__ excT,
                          float* __restrict__ counts)
{
  __shared__ float lds[64][29];
  const int n0 = blockIdx.x * 64;
  const int tid = threadIdx.x;
  for (int i = tid; i < 64 * L_SZ; i += 256) {
    const int n = i / L_SZ, l = i % L_SZ;
    lds[n][l] = (n0 + n < N_SZ) ? exc[(size_t)(n0 + n) * L_SZ + l] : 0.0f;
  }
  __syncthreads();
  if (tid < L_SZ) {
    float c = 0.f;
    for (int n = 0; n < 64; ++n) c += lds[n][tid];
    atomicAdd(&counts[tid], c);
  }
  for (int i = tid; i < 32 * 64; i += 256) {
    const int l = i >> 6, n = i & 63;
    const float v = (l < L_SZ) ? lds[n][l] : 0.0f;
    excT[(size_t)l * NP + n0 + n] = f2bf(v);
  }
}

// ---------------------------------------------------------------------------
// Fused s-GEMM, 2-phase dbuf K-loop with cross-tile prefetch. 4 n-tiles per
// block (784 blocks). Co-XCD id swizzle: id = (x%8) + 8*(m + 8*(x/8)).
// LDS: As/Bs dbuf 32KB + Al 32KB = 64KB -> 2 blocks/CU.
// ---------------------------------------------------------------------------
__global__ __launch_bounds__(256, 2)
void echo_gemm(const unsigned short* __restrict__ fn,
               const unsigned short* __restrict__ exfn,
               const unsigned short* __restrict__ excT,
               const float* __restrict__ ssqF,
               const float* __restrict__ ssqE,
               float* __restrict__ echo)
{
  const int id = blockIdx.x;
  const int slot = id & 7, rest = id >> 3;
  const int m = rest & 7, xq = rest >> 3;
  const int x = xq * 8 + slot;
  if (x >= 98) return;
  const int m0 = m * 128;

  __shared__ __align__(16) unsigned short As[2][128 * 32];
  __shared__ __align__(16) unsigned short Bs[2][128 * 32];
  __shared__ __align__(16) unsigned short Al[128 * 128];
  const int tid = threadIdx.x;
  const int w = tid >> 6, lane = tid & 63;
  const int wr = w >> 1, wc = w & 1;
  const int fr = lane & 15, fq = lane >> 4;
  const int fk = fq << 3;
  const int srow = lane >> 2;
  const int scol = (lane & 3) << 3;

  auto stage = [&](int buf, int n0s, int kk) {
#pragma unroll
    for (int i = 0; i < 2; ++i) {
      const int chunk = w * 2 + i;
      const int row = chunk * 16 + srow;
      const unsigned short* ga = fn + (size_t)(m0 + row) * D_SZ + kk + scol;
      const unsigned short* gb = exfn + (size_t)(n0s + row) * D_SZ + kk + scol;
      __builtin_amdgcn_global_load_lds((const __attribute__((address_space(1))) void*)ga,
                                       (__attribute__((address_space(3))) void*)&As[buf][chunk * 512],
                                       16, 0, 0);
      __builtin_amdgcn_global_load_lds((const __attribute__((address_space(1))) void*)gb,
                                       (__attribute__((address_space(3))) void*)&Bs[buf][chunk * 512],
                                       16, 0, 0);
    }
  };

  float rf[4][4];
#pragma unroll
  for (int mi = 0; mi < 4; ++mi)
#pragma unroll
    for (int r = 0; r < 4; ++r)
      rf[mi][r] = 1.0f / fmaxf(sqrtf(ssqF[m0 + wr * 64 + mi * 16 + fq * 4 + r]), 1e-12f);

  f32x4 acc2[2][2] = {};
  int cur = 0;
  stage(0, x * 4 * 128, 0);
  __syncthreads();

  for (int ti = 0; ti < 4; ++ti) {
    const int t = x * 4 + ti;
    if (t >= NT) break;
    const int n0 = t * 128;
    f32x4 acc[4][4] = {};
    for (int kk = 0; kk < D_SZ; kk += 32) {
      if (kk + 32 < D_SZ) stage(cur ^ 1, n0, kk + 32);
      else if (ti + 1 < 4 && t + 1 < NT) stage(cur ^ 1, n0 + 128, 0);
      bf16x8 af[4], bfv[4];
#pragma unroll
      for (int i = 0; i < 4; ++i) {
        af[i]  = *(const bf16x8*)&As[cur][(wr * 64 + i * 16 + fr) * 32 + fk];
        bfv[i] = *(const bf16x8*)&Bs[cur][(wc * 64 + i * 16 + fr) * 32 + fk];
      }
#pragma unroll
      for (int mi = 0; mi < 4; ++mi)
#pragma unroll
        for (int ni = 0; ni < 4; ++ni)
          acc[mi][ni] = __builtin_amdgcn_mfma_f32_16x16x32_bf16(af[mi], bfv[ni], acc[mi][ni], 0, 0, 0);
      __syncthreads();
      cur ^= 1;
    }
    // scale to cosine, cube, stage a = s^3 into XOR-swizzled LDS tile [b][n]
    float rne[4];
#pragma unroll
    for (int ni = 0; ni < 4; ++ni)
      rne[ni] = 1.0f / fmaxf(sqrtf(ssqE[n0 + wc * 64 + ni * 16 + fr]), 1e-12f);
#pragma unroll
    for (int mi = 0; mi < 4; ++mi)
#pragma unroll
      for (int ni = 0; ni < 4; ++ni)
#pragma unroll
        for (int r = 0; r < 4; ++r) {
          const int b = wr * 64 + mi * 16 + fq * 4 + r;
          const int n = wc * 64 + ni * 16 + fr;
          const float s = acc[mi][ni][r] * rf[mi][r] * rne[ni];
          const unsigned byte = (((unsigned)(b * 128 + n)) << 1) ^ ((unsigned)(b & 7) << 4);
          *(unsigned short*)((char*)Al + byte) = f2bf(s * s * s);
        }
    __syncthreads();
    // stage 2: echo_part[b][cls] += a[b][n] * excT[cls][n]
#pragma unroll
    for (int kk2 = 0; kk2 < 128; kk2 += 32) {
      bf16x8 pa[2], pb[2];
#pragma unroll
      for (int i = 0; i < 2; ++i) {
        const int b = w * 32 + i * 16 + fr;
        const unsigned byte = (((unsigned)(b * 128 + kk2 + fk)) << 1) ^ ((unsigned)(b & 7) << 4);
        pa[i] = *(const bf16x8*)((const char*)Al + byte);
        const int cls = i * 16 + fr;
        pb[i] = *(const bf16x8*)(excT + (size_t)cls * NP + n0 + kk2 + fk);
      }
#pragma unroll
      for (int mi = 0; mi < 2; ++mi)
#pragma unroll
        for (int ni = 0; ni < 2; ++ni)
          acc2[mi][ni] = __builtin_amdgcn_mfma_f32_16x16x32_bf16(pa[mi], pb[ni], acc2[mi][ni], 0, 0, 0);
    }
    __syncthreads();   // Al reads done before next tile's cube-write
  }
#pragma unroll
  for (int mi = 0; mi < 2; ++mi)
#pragma unroll
    for (int ni = 0; ni < 2; ++ni)
#pragma unroll
      for (int r = 0; r < 4; ++r) {
        const int b = w * 32 + mi * 16 + fq * 4 + r;
        const int cls = ni * 16 + fr;
        if (cls < L_SZ)
          atomicAdd(&echo[(size_t)(m0 + b) * L_SZ + cls], acc2[mi][ni][r]);
      }
}

// ---------------------------------------------------------------------------
// Finalize: echo/counts -> neg_dists (vs real class_reps) -> BCE loss.
// ---------------------------------------------------------------------------
__global__ __launch_bounds__(1024)
void finalize(const float* __restrict__ echo, const float* __restrict__ counts,
              const float* __restrict__ labels, const float* __restrict__ creps,
              float* __restrict__ out)
{
  __shared__ float C[L_SZ * L_SZ];
  __shared__ float cnt[L_SZ];
  __shared__ float red[16];
  const int tid = threadIdx.x;
  if (tid < L_SZ * L_SZ) C[tid] = creps[tid];
  if (tid >= 896 && tid < 896 + L_SZ) cnt[tid - 896] = counts[tid - 896];
  __syncthreads();
  float e[L_SZ];
#pragma unroll
  for (int l = 0; l < L_SZ; ++l) e[l] = echo[tid * L_SZ + l] / cnt[l];
  float lsum = 0.f;
  for (int j = 0; j < L_SZ; ++j) {
    float d2 = 0.f;
#pragma unroll
    for (int l = 0; l < L_SZ; ++l) { const float df = e[l] - C[j * L_SZ + l]; d2 += df * df; }
    const float nd = -sqrtf(d2);
    out[1 + tid * L_SZ + j] = nd;
    const float y = labels[tid * L_SZ + j];
    const float sp = fmaxf(nd, 0.f) + log1pf(expf(-fabsf(nd)));
    lsum += sp - nd * y;
  }
#pragma unroll
  for (int o = 32; o; o >>= 1) lsum += __shfl_xor(lsum, o);
  if ((tid & 63) == 0) red[tid >> 6] = lsum;
  __syncthreads();
  if (tid < 16) {
    float v = red[tid];
#pragma unroll
    for (int o = 8; o; o >>= 1) v += __shfl_xor(v, o);
    if (tid == 0) out[0] = v * (1.0f / (B_SZ * L_SZ));
  }
}

extern "C" void kernel_launch(void* const* d_in, const int* in_sizes, int n_in,
                              void* d_out, int out_size, void* d_ws, size_t ws_size,
                              hipStream_t stream)
{
  (void)in_sizes; (void)n_in; (void)out_size;
  const float* features = (const float*)d_in[0];
  const float* labels   = (const float*)d_in[1];
  const float* W_g      = (const float*)d_in[2];
  const float* ex_feat  = (const float*)d_in[3];
  const float* ex_cls   = (const float*)d_in[4];
  const float* creps    = (const float*)d_in[5];
  float* out = (float*)d_out;

  const size_t OFF_EXFN = 0;
  const size_t OFF_FN   = OFF_EXFN + (size_t)NP * D_SZ * 2;
  const size_t OFF_EXCT = OFF_FN + (size_t)B_SZ * D_SZ * 2;
  const size_t OFF_WB   = OFF_EXCT;                                // alias (disjoint lifetime)
  const size_t OFF_FNXB = OFF_EXCT + (size_t)D_SZ * D_SZ * 2;
  const size_t OFF_ECHO = OFF_EXCT + (size_t)32 * NP * 2;
  const size_t OFF_SSQE = OFF_ECHO + (size_t)B_SZ * L_SZ * 4;
  const size_t OFF_SSQF = OFF_SSQE + (size_t)NP * 4;
  const size_t OFF_CNT  = OFF_SSQF + (size_t)B_SZ * 4;
  const size_t NEED_B   = OFF_CNT + 128;
  const size_t OFF_XBE  = NEED_B;
  const size_t NEED_A   = OFF_XBE + (size_t)NP * D_SZ * 2;
  if (ws_size < NEED_B) return;
  const int useA = (ws_size >= NEED_A) ? 1 : 0;

  char* ws = (char*)d_ws;
  unsigned short* exfn = (unsigned short*)(ws + OFF_EXFN);
  unsigned short* fnb  = (unsigned short*)(ws + OFF_FN);
  unsigned short* excT = (unsigned short*)(ws + OFF_EXCT);
  unsigned short* Wb   = (unsigned short*)(ws + OFF_WB);
  unsigned short* fnXb = (unsigned short*)(ws + OFF_FNXB);
  float* echo   = (float*)(ws + OFF_ECHO);
  float* ssqE   = (float*)(ws + OFF_SSQE);
  float* ssqF   = (float*)(ws + OFF_SSQF);
  float* counts = (float*)(ws + OFF_CNT);
  unsigned short* Xbe = (unsigned short*)(ws + OFF_XBE);

  // zero echo + ssqE + ssqF + counts (contiguous span)
  hipMemsetAsync(ws + OFF_ECHO, 0, OFF_CNT + 128 - OFF_ECHO, stream);

  if (useA) {
    hipMemsetAsync((char*)Xbe + (size_t)N_SZ * D_SZ * 2, 0,
                   (size_t)(NP - N_SZ) * D_SZ * 2, stream);
    conv8<<<dim3((N_SZ * D_SZ / 8 + 255) / 256), 256, 0, stream>>>(ex_feat, Xbe, N_SZ * D_SZ / 8);
  }
  conv8<<<dim3((B_SZ * D_SZ / 8 + 255) / 256), 256, 0, stream>>>(features, fnXb, B_SZ * D_SZ / 8);
  conv8<<<dim3((D_SZ * D_SZ / 8 + 255) / 256), 256, 0, stream>>>(W_g, Wb, D_SZ * D_SZ / 8);

  // grid: id = (y%8) + 8*(x + 6*(y/8)), y in [0,399), x in [0,6)
  proj_gemm2<<<dim3(8 * 6 * 50), 256, 0, stream>>>(fnXb, Xbe, ex_feat, Wb,
                                                   fnb, exfn, ssqF, ssqE, useA);

  excT_prep<<<dim3(NP / 64), 256, 0, stream>>>(ex_cls, excT, counts);  // clobbers Wb/fnXb (done)
  // grid: id = (x%8) + 8*(m + 8*(x/8)), x in [0,98), m in [0,8)
  echo_gemm<<<dim3(8 * 8 * 13), 256, 0, stream>>>(fnb, exfn, excT, ssqF, ssqE, echo);
  finalize<<<dim3(1), 1024, 0, stream>>>(echo, counts, labels, creps, out);
}

// Round 8
// 337.454 us; speedup vs baseline: 1.5173x; 1.5173x over previous
//
#include <hip/hip_runtime.h>

#define D_SZ 768
#define N_SZ 50000
#define L_SZ 28
#define B_SZ 1024
#define NP   50048   // 391 * 128 (padded N)
#define NT   391     // n-tiles of 128

typedef __bf16 bf16x8 __attribute__((ext_vector_type(8)));
typedef float f32x4 __attribute__((ext_vector_type(4)));
typedef unsigned short u16x8 __attribute__((ext_vector_type(8)));

__device__ __forceinline__ unsigned short f2bf(float f) {
  union { float f; unsigned u; } v; v.f = f;
  unsigned r = v.u + 0x7FFFu + ((v.u >> 16) & 1u);
  return (unsigned short)(r >> 16);
}
__device__ __forceinline__ unsigned cvt_pk_bf16(float lo, float hi) {
  unsigned r;
  asm("v_cvt_pk_bf16_f32 %0, %1, %2" : "=v"(r) : "v"(lo), "v"(hi));
  return r;
}

// ---------------------------------------------------------------------------
// Streaming f32 -> bf16 convert, 8 elems/thread.
// ---------------------------------------------------------------------------
__global__ void conv8(const float* __restrict__ in, unsigned short* __restrict__ out, int n8)
{
  const int t = blockIdx.x * 256 + threadIdx.x;
  if (t >= n8) return;
  const float4 a0 = *(const float4*)(in + (size_t)t * 8);
  const float4 a1 = *(const float4*)(in + (size_t)t * 8 + 4);
  uint4 o;
  o.x = cvt_pk_bf16(a0.x, a0.y);
  o.y = cvt_pk_bf16(a0.z, a0.w);
  o.z = cvt_pk_bf16(a1.x, a1.y);
  o.w = cvt_pk_bf16(a1.z, a1.w);
  *(uint4*)(out + (size_t)t * 8) = o;
}

// ---------------------------------------------------------------------------
// Projection GEMM (round-6 known-good single-buffer form): Y = X @ W^T.
// 128x128 tile, BK=32, 4 waves. Co-XCD id swizzle.
// ---------------------------------------------------------------------------
__global__ __launch_bounds__(256, 2)
void proj_gemm2(const unsigned short* __restrict__ Xfb,
                const unsigned short* __restrict__ Xeb,
                const float* __restrict__ Xef,
                const unsigned short* __restrict__ Wb,
                unsigned short* __restrict__ Yf, unsigned short* __restrict__ Ye,
                float* __restrict__ ssqF, float* __restrict__ ssqE,
                int exBf)
{
  const int id = blockIdx.x;
  const int slot = id & 7, rest = id >> 3;
  const int x = rest % 6, yq = rest / 6;
  const int y = yq * 8 + slot;
  if (y >= 8 + NT) return;

  __shared__ __align__(16) unsigned short As[128 * 32];
  __shared__ __align__(16) unsigned short Bs[128 * 32];
  const int tid = threadIdx.x;
  const int w = tid >> 6, lane = tid & 63;
  const int wr = w >> 1, wc = w & 1;
  const int fr = lane & 15, fq = lane >> 4;
  const int fk = fq << 3;
  const int srow = lane >> 2;
  const int scol = (lane & 3) << 3;
  const int o0 = x * 128;

  const unsigned short* Xb; const float* Xf32; unsigned short* Y;
  float* ssqG; int m0, Mvalid; bool abf;
  if (y < 8) { Xb = Xfb; Xf32 = nullptr; Y = Yf; ssqG = ssqF; m0 = y * 128; Mvalid = B_SZ; abf = true; }
  else { Xb = Xeb; Xf32 = Xef; Y = Ye; ssqG = ssqE; m0 = (y - 8) * 128; Mvalid = N_SZ; abf = (exBf != 0); }

  f32x4 acc[4][4] = {};

  for (int kk = 0; kk < D_SZ; kk += 32) {
    if (abf) {
#pragma unroll
      for (int i = 0; i < 2; ++i) {
        const int chunk = w * 2 + i;
        const int row = chunk * 16 + srow;
        const unsigned short* ga = Xb + (size_t)(m0 + row) * D_SZ + kk + scol;
        __builtin_amdgcn_global_load_lds((const __attribute__((address_space(1))) void*)ga,
                                         (__attribute__((address_space(3))) void*)&As[chunk * 512],
                                         16, 0, 0);
      }
    } else {
#pragma unroll
      for (int i = 0; i < 2; ++i) {
        const int idx = tid + i * 256;
        const int row = idx >> 2;
        const int c8 = (idx & 3) << 3;
        float4 a0, a1;
        if (m0 + row < Mvalid) {
          const float* p = Xf32 + (size_t)(m0 + row) * D_SZ + kk + c8;
          a0 = *(const float4*)p; a1 = *(const float4*)(p + 4);
        } else { a0 = make_float4(0.f, 0.f, 0.f, 0.f); a1 = a0; }
        u16x8 av;
        av[0] = f2bf(a0.x); av[1] = f2bf(a0.y); av[2] = f2bf(a0.z); av[3] = f2bf(a0.w);
        av[4] = f2bf(a1.x); av[5] = f2bf(a1.y); av[6] = f2bf(a1.z); av[7] = f2bf(a1.w);
        *(u16x8*)&As[row * 32 + c8] = av;
      }
    }
#pragma unroll
    for (int i = 0; i < 2; ++i) {
      const int chunk = w * 2 + i;
      const int row = chunk * 16 + srow;
      const unsigned short* gb = Wb + (size_t)(o0 + row) * D_SZ + kk + scol;
      __builtin_amdgcn_global_load_lds((const __attribute__((address_space(1))) void*)gb,
                                       (__attribute__((address_space(3))) void*)&Bs[chunk * 512],
                                       16, 0, 0);
    }
    __syncthreads();
    bf16x8 af[4], bfv[4];
#pragma unroll
    for (int i = 0; i < 4; ++i) {
      af[i]  = *(const bf16x8*)&As[(wr * 64 + i * 16 + fr) * 32 + fk];
      bfv[i] = *(const bf16x8*)&Bs[(wc * 64 + i * 16 + fr) * 32 + fk];
    }
#pragma unroll
    for (int mi = 0; mi < 4; ++mi)
#pragma unroll
      for (int ni = 0; ni < 4; ++ni)
        acc[mi][ni] = __builtin_amdgcn_mfma_f32_16x16x32_bf16(af[mi], bfv[ni], acc[mi][ni], 0, 0, 0);
    __syncthreads();
  }

  float ssq[4][4] = {};
#pragma unroll
  for (int mi = 0; mi < 4; ++mi)
#pragma unroll
    for (int ni = 0; ni < 4; ++ni)
#pragma unroll
      for (int r = 0; r < 4; ++r) {
        const int row = m0 + wr * 64 + mi * 16 + fq * 4 + r;
        const int col = o0 + wc * 64 + ni * 16 + fr;
        const float v = acc[mi][ni][r];
        Y[(size_t)row * D_SZ + col] = f2bf(v);
        ssq[mi][r] += v * v;
      }
#pragma unroll
  for (int mi = 0; mi < 4; ++mi)
#pragma unroll
    for (int r = 0; r < 4; ++r) {
      float v = ssq[mi][r];
      v += __shfl_xor(v, 1); v += __shfl_xor(v, 2);
      v += __shfl_xor(v, 4); v += __shfl_xor(v, 8);
      if (fr == 0) atomicAdd(&ssqG[m0 + wr * 64 + mi * 16 + fq * 4 + r], v);
    }
}

// ---------------------------------------------------------------------------
// Build excT bf16 [32][NP] + fused per-class counts.
// ---------------------------------------------------------------------------
__global__ void excT_prep(const float* __restrict__ exc, unsigned short* __restrict__ excT,
                          float* __restrict__ counts)
{
  __shared__ float lds[64][29];
  const int n0 = blockIdx.x * 64;
  const int tid = threadIdx.x;
  for (int i = tid; i < 64 * L_SZ; i += 256) {
    const int n = i / L_SZ, l = i % L_SZ;
    lds[n][l] = (n0 + n < N_SZ) ? exc[(size_t)(n0 + n) * L_SZ + l] : 0.0f;
  }
  __syncthreads();
  if (tid < L_SZ) {
    float c = 0.f;
    for (int n = 0; n < 64; ++n) c += lds[n][tid];
    atomicAdd(&counts[tid], c);
  }
  for (int i = tid; i < 32 * 64; i += 256) {
    const int l = i >> 6, n = i & 63;
    const float v = (l < L_SZ) ? lds[n][l] : 0.0f;
    excT[(size_t)l * NP + n0 + n] = f2bf(v);
  }
}

// ---------------------------------------------------------------------------
// Fused s-GEMM with T4 counted-vmcnt pipeline. 8 n-tiles/block, 448 blocks,
// co-XCD swizzle. K-loop per step: stage(next) -> vmcnt(4) -> s_barrier ->
// ds_read+MFMA -> lgkmcnt(0) -> s_barrier. Prefetch loads stay in flight
// across both barriers (never drained to 0 except at tile end).
// Invariant at each wait: 8 outstanding, oldest 4 = current buffer.
// ---------------------------------------------------------------------------
__global__ __launch_bounds__(256, 2)
void echo_gemm(const unsigned short* __restrict__ fn,
               const unsigned short* __restrict__ exfn,
               const unsigned short* __restrict__ excT,
               const float* __restrict__ ssqF,
               const float* __restrict__ ssqE,
               float* __restrict__ echo)
{
  const int id = blockIdx.x;
  const int slot = id & 7, rest = id >> 3;
  const int m = rest & 7, xq = rest >> 3;
  const int x = xq * 8 + slot;
  if (x >= 49) return;
  const int m0 = m * 128;
  const int ntile = (NT - x * 8 < 8) ? (NT - x * 8) : 8;

  __shared__ __align__(16) unsigned short As[2][128 * 32];
  __shared__ __align__(16) unsigned short Bs[2][128 * 32];
  __shared__ __align__(16) unsigned short Al[128 * 128];
  const int tid = threadIdx.x;
  const int w = tid >> 6, lane = tid & 63;
  const int wr = w >> 1, wc = w & 1;
  const int fr = lane & 15, fq = lane >> 4;
  const int fk = fq << 3;
  const int srow = lane >> 2;
  const int scol = (lane & 3) << 3;

  auto stage = [&](int buf, int n0s, int kk) {
#pragma unroll
    for (int i = 0; i < 2; ++i) {
      const int chunk = w * 2 + i;
      const int row = chunk * 16 + srow;
      const unsigned short* ga = fn + (size_t)(m0 + row) * D_SZ + kk + scol;
      const unsigned short* gb = exfn + (size_t)(n0s + row) * D_SZ + kk + scol;
      __builtin_amdgcn_global_load_lds((const __attribute__((address_space(1))) void*)ga,
                                       (__attribute__((address_space(3))) void*)&As[buf][chunk * 512],
                                       16, 0, 0);
      __builtin_amdgcn_global_load_lds((const __attribute__((address_space(1))) void*)gb,
                                       (__attribute__((address_space(3))) void*)&Bs[buf][chunk * 512],
                                       16, 0, 0);
    }
  };

  float rf[4][4];
#pragma unroll
  for (int mi = 0; mi < 4; ++mi)
#pragma unroll
    for (int r = 0; r < 4; ++r)
      rf[mi][r] = 1.0f / fmaxf(sqrtf(ssqF[m0 + wr * 64 + mi * 16 + fq * 4 + r]), 1e-12f);

  f32x4 acc2[2][2] = {};
  int cur = 0;
  stage(0, x * 8 * 128, 0);   // prologue: tile-0 k0 in flight

  for (int ti = 0; ti < ntile; ++ti) {
    const int n0 = (x * 8 + ti) * 128;
    f32x4 acc[4][4] = {};
    for (int kk = 0; kk < D_SZ; kk += 32) {
      if (kk + 32 < D_SZ) {
        stage(cur ^ 1, n0, kk + 32);                    // outstanding: cur(4) + next(4)
        asm volatile("s_waitcnt vmcnt(4)" ::: "memory"); // wait oldest 4 = cur
      } else {
        asm volatile("s_waitcnt vmcnt(0)" ::: "memory"); // tile end: drain cur
      }
      __builtin_amdgcn_s_barrier();                      // cur visible to all waves
      bf16x8 af[4], bfv[4];
#pragma unroll
      for (int i = 0; i < 4; ++i) {
        af[i]  = *(const bf16x8*)&As[cur][(wr * 64 + i * 16 + fr) * 32 + fk];
        bfv[i] = *(const bf16x8*)&Bs[cur][(wc * 64 + i * 16 + fr) * 32 + fk];
      }
#pragma unroll
      for (int mi = 0; mi < 4; ++mi)
#pragma unroll
        for (int ni = 0; ni < 4; ++ni)
          acc[mi][ni] = __builtin_amdgcn_mfma_f32_16x16x32_bf16(af[mi], bfv[ni], acc[mi][ni], 0, 0, 0);
      asm volatile("s_waitcnt lgkmcnt(0)" ::: "memory"); // my ds_reads of cur done
      __builtin_amdgcn_s_barrier();                      // everyone's done -> safe to overwrite
      __builtin_amdgcn_sched_barrier(0);                 // pin: no hoist above barrier
      cur ^= 1;
    }
    // cube + stage a = s^3 into XOR-swizzled LDS tile [b][n]
    float rne[4];
#pragma unroll
    for (int ni = 0; ni < 4; ++ni)
      rne[ni] = 1.0f / fmaxf(sqrtf(ssqE[n0 + wc * 64 + ni * 16 + fr]), 1e-12f);
#pragma unroll
    for (int mi = 0; mi < 4; ++mi)
#pragma unroll
      for (int ni = 0; ni < 4; ++ni)
#pragma unroll
        for (int r = 0; r < 4; ++r) {
          const int b = wr * 64 + mi * 16 + fq * 4 + r;
          const int n = wc * 64 + ni * 16 + fr;
          const float s = acc[mi][ni][r] * rf[mi][r] * rne[ni];
          const unsigned byte = (((unsigned)(b * 128 + n)) << 1) ^ ((unsigned)(b & 7) << 4);
          *(unsigned short*)((char*)Al + byte) = f2bf(s * s * s);
        }
    asm volatile("s_waitcnt lgkmcnt(0)" ::: "memory");
    __builtin_amdgcn_s_barrier();
    // phase-2: echo_part[b][cls] += a[b][n] * excT[cls][n]
#pragma unroll
    for (int kk2 = 0; kk2 < 128; kk2 += 32) {
      bf16x8 pa[2], pb[2];
#pragma unroll
      for (int i = 0; i < 2; ++i) {
        const int b = w * 32 + i * 16 + fr;
        const unsigned byte = (((unsigned)(b * 128 + kk2 + fk)) << 1) ^ ((unsigned)(b & 7) << 4);
        pa[i] = *(const bf16x8*)((const char*)Al + byte);
        const int cls = i * 16 + fr;
        pb[i] = *(const bf16x8*)(excT + (size_t)cls * NP + n0 + kk2 + fk);
      }
#pragma unroll
      for (int mi = 0; mi < 2; ++mi)
#pragma unroll
        for (int ni = 0; ni < 2; ++ni)
          acc2[mi][ni] = __builtin_amdgcn_mfma_f32_16x16x32_bf16(pa[mi], pb[ni], acc2[mi][ni], 0, 0, 0);
    }
    asm volatile("s_waitcnt lgkmcnt(0)" ::: "memory");   // Al reads done
    __builtin_amdgcn_s_barrier();
    __builtin_amdgcn_sched_barrier(0);
    if (ti + 1 < ntile) stage(cur, n0 + 128, 0);         // next tile k0: issued AFTER
                                                         // phase-2 waits so it survives
  }
#pragma unroll
  for (int mi = 0; mi < 2; ++mi)
#pragma unroll
    for (int ni = 0; ni < 2; ++ni)
#pragma unroll
      for (int r = 0; r < 4; ++r) {
        const int b = w * 32 + mi * 16 + fq * 4 + r;
        const int cls = ni * 16 + fr;
        if (cls < L_SZ)
          atomicAdd(&echo[(size_t)(m0 + b) * L_SZ + cls], acc2[mi][ni][r]);
      }
}

// ---------------------------------------------------------------------------
// Finalize: echo/counts -> neg_dists (vs real class_reps) -> BCE loss.
// ---------------------------------------------------------------------------
__global__ __launch_bounds__(1024)
void finalize(const float* __restrict__ echo, const float* __restrict__ counts,
              const float* __restrict__ labels, const float* __restrict__ creps,
              float* __restrict__ out)
{
  __shared__ float C[L_SZ * L_SZ];
  __shared__ float cnt[L_SZ];
  __shared__ float red[16];
  const int tid = threadIdx.x;
  if (tid < L_SZ * L_SZ) C[tid] = creps[tid];
  if (tid >= 896 && tid < 896 + L_SZ) cnt[tid - 896] = counts[tid - 896];
  __syncthreads();
  float e[L_SZ];
#pragma unroll
  for (int l = 0; l < L_SZ; ++l) e[l] = echo[tid * L_SZ + l] / cnt[l];
  float lsum = 0.f;
  for (int j = 0; j < L_SZ; ++j) {
    float d2 = 0.f;
#pragma unroll
    for (int l = 0; l < L_SZ; ++l) { const float df = e[l] - C[j * L_SZ + l]; d2 += df * df; }
    const float nd = -sqrtf(d2);
    out[1 + tid * L_SZ + j] = nd;
    const float y = labels[tid * L_SZ + j];
    const float sp = fmaxf(nd, 0.f) + log1pf(expf(-fabsf(nd)));
    lsum += sp - nd * y;
  }
#pragma unroll
  for (int o = 32; o; o >>= 1) lsum += __shfl_xor(lsum, o);
  if ((tid & 63) == 0) red[tid >> 6] = lsum;
  __syncthreads();
  if (tid < 16) {
    float v = red[tid];
#pragma unroll
    for (int o = 8; o; o >>= 1) v += __shfl_xor(v, o);
    if (tid == 0) out[0] = v * (1.0f / (B_SZ * L_SZ));
  }
}

extern "C" void kernel_launch(void* const* d_in, const int* in_sizes, int n_in,
                              void* d_out, int out_size, void* d_ws, size_t ws_size,
                              hipStream_t stream)
{
  (void)in_sizes; (void)n_in; (void)out_size;
  const float* features = (const float*)d_in[0];
  const float* labels   = (const float*)d_in[1];
  const float* W_g      = (const float*)d_in[2];
  const float* ex_feat  = (const float*)d_in[3];
  const float* ex_cls   = (const float*)d_in[4];
  const float* creps    = (const float*)d_in[5];
  float* out = (float*)d_out;

  const size_t OFF_EXFN = 0;
  const size_t OFF_FN   = OFF_EXFN + (size_t)NP * D_SZ * 2;
  const size_t OFF_EXCT = OFF_FN + (size_t)B_SZ * D_SZ * 2;
  const size_t OFF_WB   = OFF_EXCT;                                // alias (disjoint lifetime)
  const size_t OFF_FNXB = OFF_EXCT + (size_t)D_SZ * D_SZ * 2;
  const size_t OFF_ECHO = OFF_EXCT + (size_t)32 * NP * 2;
  const size_t OFF_SSQE = OFF_ECHO + (size_t)B_SZ * L_SZ * 4;
  const size_t OFF_SSQF = OFF_SSQE + (size_t)NP * 4;
  const size_t OFF_CNT  = OFF_SSQF + (size_t)B_SZ * 4;
  const size_t NEED_B   = OFF_CNT + 128;
  const size_t OFF_XBE  = NEED_B;
  const size_t NEED_A   = OFF_XBE + (size_t)NP * D_SZ * 2;
  if (ws_size < NEED_B) return;
  const int useA = (ws_size >= NEED_A) ? 1 : 0;

  char* ws = (char*)d_ws;
  unsigned short* exfn = (unsigned short*)(ws + OFF_EXFN);
  unsigned short* fnb  = (unsigned short*)(ws + OFF_FN);
  unsigned short* excT = (unsigned short*)(ws + OFF_EXCT);
  unsigned short* Wb   = (unsigned short*)(ws + OFF_WB);
  unsigned short* fnXb = (unsigned short*)(ws + OFF_FNXB);
  float* echo   = (float*)(ws + OFF_ECHO);
  float* ssqE   = (float*)(ws + OFF_SSQE);
  float* ssqF   = (float*)(ws + OFF_SSQF);
  float* counts = (float*)(ws + OFF_CNT);
  unsigned short* Xbe = (unsigned short*)(ws + OFF_XBE);

  // zero echo + ssqE + ssqF + counts (contiguous span)
  hipMemsetAsync(ws + OFF_ECHO, 0, OFF_CNT + 128 - OFF_ECHO, stream);

  if (useA) {
    hipMemsetAsync((char*)Xbe + (size_t)N_SZ * D_SZ * 2, 0,
                   (size_t)(NP - N_SZ) * D_SZ * 2, stream);
    conv8<<<dim3((N_SZ * D_SZ / 8 + 255) / 256), 256, 0, stream>>>(ex_feat, Xbe, N_SZ * D_SZ / 8);
  }
  conv8<<<dim3((B_SZ * D_SZ / 8 + 255) / 256), 256, 0, stream>>>(features, fnXb, B_SZ * D_SZ / 8);
  conv8<<<dim3((D_SZ * D_SZ / 8 + 255) / 256), 256, 0, stream>>>(W_g, Wb, D_SZ * D_SZ / 8);

  // grid: id = (y%8) + 8*(x + 6*(y/8)), y in [0,399), x in [0,6)
  proj_gemm2<<<dim3(8 * 6 * 50), 256, 0, stream>>>(fnXb, Xbe, ex_feat, Wb,
                                                   fnb, exfn, ssqF, ssqE, useA);

  excT_prep<<<dim3(NP / 64), 256, 0, stream>>>(ex_cls, excT, counts);  // clobbers Wb/fnXb (done)
  // grid: id = (x%8) + 8*(m + 8*(x/8)), x in [0,49), m in [0,8)
  echo_gemm<<<dim3(8 * 8 * 7), 256, 0, stream>>>(fnb, exfn, excT, ssqF, ssqE, echo);
  finalize<<<dim3(1), 1024, 0, stream>>>(echo, counts, labels, creps, out);
}

// Round 9
// 314.626 us; speedup vs baseline: 1.6274x; 1.0726x over previous
//
#include <hip/hip_runtime.h>

#define D_SZ 768
#define N_SZ 50000
#define L_SZ 28
#define B_SZ 1024
#define NP   50048   // 391 * 128 (padded N)
#define NT   391     // n-tiles of 128

typedef __bf16 bf16x8 __attribute__((ext_vector_type(8)));
typedef float f32x4 __attribute__((ext_vector_type(4)));
typedef unsigned short u16x8 __attribute__((ext_vector_type(8)));
typedef int i32x8 __attribute__((ext_vector_type(8)));

__device__ __forceinline__ unsigned short f2bf(float f) {
  union { float f; unsigned u; } v; v.f = f;
  unsigned r = v.u + 0x7FFFu + ((v.u >> 16) & 1u);
  return (unsigned short)(r >> 16);
}
__device__ __forceinline__ unsigned cvt_pk_bf16(float lo, float hi) {
  unsigned r;
  asm("v_cvt_pk_bf16_f32 %0, %1, %2" : "=v"(r) : "v"(lo), "v"(hi));
  return r;
}
// byte-order-proof single fp8 e4m3 convert (both packed bytes equal)
__device__ __forceinline__ unsigned char f2fp8(float a) {
  unsigned r;
  asm("v_cvt_pk_fp8_f32 %0, %1, %2" : "=v"(r) : "v"(a), "v"(a));
  return (unsigned char)(r & 0xFF);
}
__device__ __forceinline__ i32x8 mk8(uint4 lo, uint4 hi) {
  i32x8 r;
  r[0] = (int)lo.x; r[1] = (int)lo.y; r[2] = (int)lo.z; r[3] = (int)lo.w;
  r[4] = (int)hi.x; r[5] = (int)hi.y; r[6] = (int)hi.z; r[7] = (int)hi.w;
  return r;
}
// fp8 e4m3 x fp8 e4m3, K=128, scales = 1.0 (E8M0 0x7F in every byte)
#define MFMA_FP8(a, b, c) \
  __builtin_amdgcn_mfma_scale_f32_16x16x128_f8f6f4((a), (b), (c), 0, 0, \
                                                   0, 0x7F7F7F7F, 0, 0x7F7F7F7F)

// ---------------------------------------------------------------------------
// Streaming f32 -> bf16 convert, 8 elems/thread.
// ---------------------------------------------------------------------------
__global__ void conv8(const float* __restrict__ in, unsigned short* __restrict__ out, int n8)
{
  const int t = blockIdx.x * 256 + threadIdx.x;
  if (t >= n8) return;
  const float4 a0 = *(const float4*)(in + (size_t)t * 8);
  const float4 a1 = *(const float4*)(in + (size_t)t * 8 + 4);
  uint4 o;
  o.x = cvt_pk_bf16(a0.x, a0.y);
  o.y = cvt_pk_bf16(a0.z, a0.w);
  o.z = cvt_pk_bf16(a1.x, a1.y);
  o.w = cvt_pk_bf16(a1.z, a1.w);
  *(uint4*)(out + (size_t)t * 8) = o;
}

// ---------------------------------------------------------------------------
// Projection GEMM (round-6 structure): bf16 MFMA, but epilogue emits fp8 Y
// plus exact per-row sum-of-squares (from f32 acc) -> global atomics.
// Co-XCD id swizzle: id = (y%8) + 8*(x + 6*(y/8)).
// ---------------------------------------------------------------------------
__global__ __launch_bounds__(256, 2)
void proj_gemm2(const unsigned short* __restrict__ Xfb,
                const unsigned short* __restrict__ Xeb,
                const float* __restrict__ Xef,
                const unsigned short* __restrict__ Wb,
                unsigned char* __restrict__ Yf8, unsigned char* __restrict__ Ye8,
                float* __restrict__ ssqF, float* __restrict__ ssqE,
                int exBf)
{
  const int id = blockIdx.x;
  const int slot = id & 7, rest = id >> 3;
  const int x = rest % 6, yq = rest / 6;
  const int y = yq * 8 + slot;
  if (y >= 8 + NT) return;

  __shared__ __align__(16) unsigned short As[128 * 32];
  __shared__ __align__(16) unsigned short Bs[128 * 32];
  const int tid = threadIdx.x;
  const int w = tid >> 6, lane = tid & 63;
  const int wr = w >> 1, wc = w & 1;
  const int fr = lane & 15, fq = lane >> 4;
  const int fk = fq << 3;
  const int srow = lane >> 2;
  const int scol = (lane & 3) << 3;
  const int o0 = x * 128;

  const unsigned short* Xb; const float* Xf32; unsigned char* Y8;
  float* ssqG; int m0, Mvalid; bool abf;
  if (y < 8) { Xb = Xfb; Xf32 = nullptr; Y8 = Yf8; ssqG = ssqF; m0 = y * 128; Mvalid = B_SZ; abf = true; }
  else { Xb = Xeb; Xf32 = Xef; Y8 = Ye8; ssqG = ssqE; m0 = (y - 8) * 128; Mvalid = N_SZ; abf = (exBf != 0); }

  f32x4 acc[4][4] = {};

  for (int kk = 0; kk < D_SZ; kk += 32) {
    if (abf) {
#pragma unroll
      for (int i = 0; i < 2; ++i) {
        const int chunk = w * 2 + i;
        const int row = chunk * 16 + srow;
        const unsigned short* ga = Xb + (size_t)(m0 + row) * D_SZ + kk + scol;
        __builtin_amdgcn_global_load_lds((const __attribute__((address_space(1))) void*)ga,
                                         (__attribute__((address_space(3))) void*)&As[chunk * 512],
                                         16, 0, 0);
      }
    } else {
#pragma unroll
      for (int i = 0; i < 2; ++i) {
        const int idx = tid + i * 256;
        const int row = idx >> 2;
        const int c8 = (idx & 3) << 3;
        float4 a0, a1;
        if (m0 + row < Mvalid) {
          const float* p = Xf32 + (size_t)(m0 + row) * D_SZ + kk + c8;
          a0 = *(const float4*)p; a1 = *(const float4*)(p + 4);
        } else { a0 = make_float4(0.f, 0.f, 0.f, 0.f); a1 = a0; }
        u16x8 av;
        av[0] = f2bf(a0.x); av[1] = f2bf(a0.y); av[2] = f2bf(a0.z); av[3] = f2bf(a0.w);
        av[4] = f2bf(a1.x); av[5] = f2bf(a1.y); av[6] = f2bf(a1.z); av[7] = f2bf(a1.w);
        *(u16x8*)&As[row * 32 + c8] = av;
      }
    }
#pragma unroll
    for (int i = 0; i < 2; ++i) {
      const int chunk = w * 2 + i;
      const int row = chunk * 16 + srow;
      const unsigned short* gb = Wb + (size_t)(o0 + row) * D_SZ + kk + scol;
      __builtin_amdgcn_global_load_lds((const __attribute__((address_space(1))) void*)gb,
                                       (__attribute__((address_space(3))) void*)&Bs[chunk * 512],
                                       16, 0, 0);
    }
    __syncthreads();
    bf16x8 af[4], bfv[4];
#pragma unroll
    for (int i = 0; i < 4; ++i) {
      af[i]  = *(const bf16x8*)&As[(wr * 64 + i * 16 + fr) * 32 + fk];
      bfv[i] = *(const bf16x8*)&Bs[(wc * 64 + i * 16 + fr) * 32 + fk];
    }
#pragma unroll
    for (int mi = 0; mi < 4; ++mi)
#pragma unroll
      for (int ni = 0; ni < 4; ++ni)
        acc[mi][ni] = __builtin_amdgcn_mfma_f32_16x16x32_bf16(af[mi], bfv[ni], acc[mi][ni], 0, 0, 0);
    __syncthreads();
  }

  float ssq[4][4] = {};
#pragma unroll
  for (int mi = 0; mi < 4; ++mi)
#pragma unroll
    for (int ni = 0; ni < 4; ++ni)
#pragma unroll
      for (int r = 0; r < 4; ++r) {
        const int row = m0 + wr * 64 + mi * 16 + fq * 4 + r;
        const int col = o0 + wc * 64 + ni * 16 + fr;
        const float v = acc[mi][ni][r];
        Y8[(size_t)row * D_SZ + col] = f2fp8(v);
        ssq[mi][r] += v * v;
      }
#pragma unroll
  for (int mi = 0; mi < 4; ++mi)
#pragma unroll
    for (int r = 0; r < 4; ++r) {
      float v = ssq[mi][r];
      v += __shfl_xor(v, 1); v += __shfl_xor(v, 2);
      v += __shfl_xor(v, 4); v += __shfl_xor(v, 8);
      if (fr == 0) atomicAdd(&ssqG[m0 + wr * 64 + mi * 16 + fq * 4 + r], v);
    }
}

// ---------------------------------------------------------------------------
// Build excT fp8 [32][NP] (exact 0x38 = 1.0 / 0x00 = 0.0) + fused counts.
// ---------------------------------------------------------------------------
__global__ void excT_prep(const float* __restrict__ exc, unsigned char* __restrict__ excT8,
                          float* __restrict__ counts)
{
  __shared__ float lds[64][29];
  const int n0 = blockIdx.x * 64;
  const int tid = threadIdx.x;
  for (int i = tid; i < 64 * L_SZ; i += 256) {
    const int n = i / L_SZ, l = i % L_SZ;
    lds[n][l] = (n0 + n < N_SZ) ? exc[(size_t)(n0 + n) * L_SZ + l] : 0.0f;
  }
  __syncthreads();
  if (tid < L_SZ) {
    float c = 0.f;
    for (int n = 0; n < 64; ++n) c += lds[n][tid];
    atomicAdd(&counts[tid], c);
  }
  for (int i = tid; i < 32 * 64; i += 256) {
    const int l = i >> 6, n = i & 63;
    const unsigned char v = (l < L_SZ && lds[n][l] != 0.0f) ? 0x38 : 0x00;
    excT8[(size_t)l * NP + n0 + n] = v;
  }
}

// ---------------------------------------------------------------------------
// Fused s-GEMM, MX-fp8 K=128 (scales = 1.0). 8 n-tiles/block, 448 blocks,
// co-XCD swizzle, round-8 counted-vmcnt skeleton (vmcnt(8), raw s_barrier).
// LDS: As/Bs fp8 dbuf 64KB + Al fp8 16KB = 80KB -> 2 blocks/CU.
// Staging swizzle: LDS slot s of row r holds k-chunk s^(r&7), realized by
// pre-swizzled GLOBAL source (linear global_load_lds dest). Fragment reads
// then hit 8 lanes per 16B bank-window = conflict-free.
// ---------------------------------------------------------------------------
__global__ __launch_bounds__(256, 2)
void echo_gemm8(const unsigned char* __restrict__ fn8,
                const unsigned char* __restrict__ exfn8,
                const unsigned char* __restrict__ excT8,
                const float* __restrict__ ssqF,
                const float* __restrict__ ssqE,
                float* __restrict__ echo)
{
  const int id = blockIdx.x;
  const int slot = id & 7, rest = id >> 3;
  const int m = rest & 7, xq = rest >> 3;
  const int x = xq * 8 + slot;
  if (x >= 49) return;
  const int m0 = m * 128;
  const int ntile = (NT - x * 8 < 8) ? (NT - x * 8) : 8;

  __shared__ __align__(16) unsigned char As8[2][128 * 128];
  __shared__ __align__(16) unsigned char Bs8[2][128 * 128];
  __shared__ __align__(16) unsigned char Al8[128 * 128];
  const int tid = threadIdx.x;
  const int w = tid >> 6, lane = tid & 63;
  const int wr = w >> 1, wc = w & 1;
  const int fr = lane & 15, fq = lane >> 4;

  // staging constants: wave instr i covers rows w*32+i*8 .. +8 (1024 B linear)
  const int srow = lane >> 3;                 // 0..7
  const int schunk = (lane & 7) ^ srow;       // pre-swizzled global 16B-chunk

  auto stage = [&](int buf, int n0s, int kk) {
#pragma unroll
    for (int i = 0; i < 4; ++i) {
      const int row = w * 32 + i * 8 + srow;
      const unsigned char* ga = fn8 + (size_t)(m0 + row) * D_SZ + kk + schunk * 16;
      const unsigned char* gb = exfn8 + (size_t)(n0s + row) * D_SZ + kk + schunk * 16;
      __builtin_amdgcn_global_load_lds((const __attribute__((address_space(1))) void*)ga,
                                       (__attribute__((address_space(3))) void*)&As8[buf][(w * 32 + i * 8) * 128],
                                       16, 0, 0);
      __builtin_amdgcn_global_load_lds((const __attribute__((address_space(1))) void*)gb,
                                       (__attribute__((address_space(3))) void*)&Bs8[buf][(w * 32 + i * 8) * 128],
                                       16, 0, 0);
    }
  };

  float rf[4][4];
#pragma unroll
  for (int mi = 0; mi < 4; ++mi)
#pragma unroll
    for (int r = 0; r < 4; ++r)
      rf[mi][r] = 1.0f / fmaxf(sqrtf(ssqF[m0 + wr * 64 + mi * 16 + fq * 4 + r]), 1e-12f);

  f32x4 acc2[2][2] = {};
  int cur = 0;
  stage(0, x * 8 * 128, 0);   // prologue: tile-0 k0 in flight (8 loads/wave)

  for (int ti = 0; ti < ntile; ++ti) {
    const int n0 = (x * 8 + ti) * 128;
    f32x4 acc[4][4] = {};
    for (int kk = 0; kk < D_SZ; kk += 128) {
      if (kk + 128 < D_SZ) {
        stage(cur ^ 1, n0, kk + 128);                    // 8 newer in flight
        asm volatile("s_waitcnt vmcnt(8)" ::: "memory"); // wait oldest 8 = cur
      } else {
        asm volatile("s_waitcnt vmcnt(0)" ::: "memory");
      }
      __builtin_amdgcn_s_barrier();
      i32x8 af[4], bfv[4];
#pragma unroll
      for (int i = 0; i < 4; ++i) {
        {
          const int row = wr * 64 + i * 16 + fr;
          const int r7 = row & 7;
          const unsigned char* rb = &As8[cur][row * 128];
          const uint4 lo = *(const uint4*)(rb + (((2 * fq + 0) ^ r7) << 4));
          const uint4 hi = *(const uint4*)(rb + (((2 * fq + 1) ^ r7) << 4));
          af[i] = mk8(lo, hi);
        }
        {
          const int row = wc * 64 + i * 16 + fr;
          const int r7 = row & 7;
          const unsigned char* rb = &Bs8[cur][row * 128];
          const uint4 lo = *(const uint4*)(rb + (((2 * fq + 0) ^ r7) << 4));
          const uint4 hi = *(const uint4*)(rb + (((2 * fq + 1) ^ r7) << 4));
          bfv[i] = mk8(lo, hi);
        }
      }
#pragma unroll
      for (int mi = 0; mi < 4; ++mi)
#pragma unroll
        for (int ni = 0; ni < 4; ++ni)
          acc[mi][ni] = MFMA_FP8(af[mi], bfv[ni], acc[mi][ni]);
      asm volatile("s_waitcnt lgkmcnt(0)" ::: "memory");
      __builtin_amdgcn_s_barrier();
      __builtin_amdgcn_sched_barrier(0);
      cur ^= 1;
    }
    // cube: a = 64 * s^3 as fp8 into swizzled Al8 (slot s holds n-chunk s^(b&7))
    float rne[4];
#pragma unroll
    for (int ni = 0; ni < 4; ++ni)
      rne[ni] = 1.0f / fmaxf(sqrtf(ssqE[n0 + wc * 64 + ni * 16 + fr]), 1e-12f);
#pragma unroll
    for (int mi = 0; mi < 4; ++mi)
#pragma unroll
      for (int ni = 0; ni < 4; ++ni)
#pragma unroll
        for (int r = 0; r < 4; ++r) {
          const int b = wr * 64 + mi * 16 + fq * 4 + r;
          const int n = wc * 64 + ni * 16 + fr;
          const float s = acc[mi][ni][r] * rf[mi][r] * rne[ni];
          const unsigned byte = (unsigned)(b * 128) + ((((unsigned)(n >> 4)) ^ ((unsigned)b & 7u)) << 4) + ((unsigned)n & 15u);
          Al8[byte] = f2fp8(s * s * s * 64.0f);
        }
    asm volatile("s_waitcnt lgkmcnt(0)" ::: "memory");
    __builtin_amdgcn_s_barrier();
    // phase-2: echo[b][cls] += a[b][n] * excT[cls][n], one K=128 MFMA per frag
    {
      i32x8 pa[2], pb[2];
#pragma unroll
      for (int i = 0; i < 2; ++i) {
        const int row = w * 32 + i * 16 + fr;
        const int r7 = row & 7;
        const unsigned char* rb = &Al8[row * 128];
        const uint4 lo = *(const uint4*)(rb + (((2 * fq + 0) ^ r7) << 4));
        const uint4 hi = *(const uint4*)(rb + (((2 * fq + 1) ^ r7) << 4));
        pa[i] = mk8(lo, hi);
        const unsigned char* gp = excT8 + (size_t)(i * 16 + fr) * NP + n0 + fq * 32;
        const uint4 glo = *(const uint4*)gp;
        const uint4 ghi = *(const uint4*)(gp + 16);
        pb[i] = mk8(glo, ghi);
      }
#pragma unroll
      for (int mi = 0; mi < 2; ++mi)
#pragma unroll
        for (int ni = 0; ni < 2; ++ni)
          acc2[mi][ni] = MFMA_FP8(pa[mi], pb[ni], acc2[mi][ni]);
    }
    asm volatile("s_waitcnt lgkmcnt(0)" ::: "memory");
    __builtin_amdgcn_s_barrier();
    __builtin_amdgcn_sched_barrier(0);
    if (ti + 1 < ntile) stage(cur, n0 + 128, 0);
  }
#pragma unroll
  for (int mi = 0; mi < 2; ++mi)
#pragma unroll
    for (int ni = 0; ni < 2; ++ni)
#pragma unroll
      for (int r = 0; r < 4; ++r) {
        const int b = w * 32 + mi * 16 + fq * 4 + r;
        const int cls = ni * 16 + fr;
        if (cls < L_SZ)
          atomicAdd(&echo[(size_t)(m0 + b) * L_SZ + cls], acc2[mi][ni][r] * (1.0f / 64.0f));
      }
}

// ---------------------------------------------------------------------------
// Finalize: echo/counts -> neg_dists (vs real class_reps) -> BCE loss.
// ---------------------------------------------------------------------------
__global__ __launch_bounds__(1024)
void finalize(const float* __restrict__ echo, const float* __restrict__ counts,
              const float* __restrict__ labels, const float* __restrict__ creps,
              float* __restrict__ out)
{
  __shared__ float C[L_SZ * L_SZ];
  __shared__ float cnt[L_SZ];
  __shared__ float red[16];
  const int tid = threadIdx.x;
  if (tid < L_SZ * L_SZ) C[tid] = creps[tid];
  if (tid >= 896 && tid < 896 + L_SZ) cnt[tid - 896] = counts[tid - 896];
  __syncthreads();
  float e[L_SZ];
#pragma unroll
  for (int l = 0; l < L_SZ; ++l) e[l] = echo[tid * L_SZ + l] / cnt[l];
  float lsum = 0.f;
  for (int j = 0; j < L_SZ; ++j) {
    float d2 = 0.f;
#pragma unroll
    for (int l = 0; l < L_SZ; ++l) { const float df = e[l] - C[j * L_SZ + l]; d2 += df * df; }
    const float nd = -sqrtf(d2);
    out[1 + tid * L_SZ + j] = nd;
    const float y = labels[tid * L_SZ + j];
    const float sp = fmaxf(nd, 0.f) + log1pf(expf(-fabsf(nd)));
    lsum += sp - nd * y;
  }
#pragma unroll
  for (int o = 32; o; o >>= 1) lsum += __shfl_xor(lsum, o);
  if ((tid & 63) == 0) red[tid >> 6] = lsum;
  __syncthreads();
  if (tid < 16) {
    float v = red[tid];
#pragma unroll
    for (int o = 8; o; o >>= 1) v += __shfl_xor(v, o);
    if (tid == 0) out[0] = v * (1.0f / (B_SZ * L_SZ));
  }
}

extern "C" void kernel_launch(void* const* d_in, const int* in_sizes, int n_in,
                              void* d_out, int out_size, void* d_ws, size_t ws_size,
                              hipStream_t stream)
{
  (void)in_sizes; (void)n_in; (void)out_size;
  const float* features = (const float*)d_in[0];
  const float* labels   = (const float*)d_in[1];
  const float* W_g      = (const float*)d_in[2];
  const float* ex_feat  = (const float*)d_in[3];
  const float* ex_cls   = (const float*)d_in[4];
  const float* creps    = (const float*)d_in[5];
  float* out = (float*)d_out;

  const size_t OFF_EXFN8 = 0;                                        // NP*768 = 38,436,864
  const size_t OFF_FN8   = OFF_EXFN8 + (size_t)NP * D_SZ;            // + 786,432
  const size_t OFF_EXCT8 = OFF_FN8 + (size_t)B_SZ * D_SZ;            // + 1,601,536
  const size_t OFF_WB    = OFF_EXCT8 + (size_t)32 * NP;              // + 1,179,648 (bf16 W)
  const size_t OFF_FNXB  = OFF_WB + (size_t)D_SZ * D_SZ * 2;         // + 1,572,864 (bf16 features)
  const size_t OFF_ECHO  = OFF_FNXB + (size_t)B_SZ * D_SZ * 2;       // + 114,688
  const size_t OFF_SSQE  = OFF_ECHO + (size_t)B_SZ * L_SZ * 4;       // + 200,192
  const size_t OFF_SSQF  = OFF_SSQE + (size_t)NP * 4;                // + 4,096
  const size_t OFF_CNT   = OFF_SSQF + (size_t)B_SZ * 4;              // + 128
  const size_t NEED_B    = OFF_CNT + 128;
  const size_t OFF_XBE   = NEED_B;                                   // bf16 ex_features
  const size_t NEED_A    = OFF_XBE + (size_t)NP * D_SZ * 2;          // ~120.8 MB
  if (ws_size < NEED_B) return;
  const int useA = (ws_size >= NEED_A) ? 1 : 0;

  char* ws = (char*)d_ws;
  unsigned char* exfn8 = (unsigned char*)(ws + OFF_EXFN8);
  unsigned char* fn8   = (unsigned char*)(ws + OFF_FN8);
  unsigned char* excT8 = (unsigned char*)(ws + OFF_EXCT8);
  unsigned short* Wb   = (unsigned short*)(ws + OFF_WB);
  unsigned short* fnXb = (unsigned short*)(ws + OFF_FNXB);
  float* echo   = (float*)(ws + OFF_ECHO);
  float* ssqE   = (float*)(ws + OFF_SSQE);
  float* ssqF   = (float*)(ws + OFF_SSQF);
  float* counts = (float*)(ws + OFF_CNT);
  unsigned short* Xbe = (unsigned short*)(ws + OFF_XBE);

  // zero echo + ssqE + ssqF + counts (contiguous span)
  hipMemsetAsync(ws + OFF_ECHO, 0, OFF_CNT + 128 - OFF_ECHO, stream);

  if (useA) {
    hipMemsetAsync((char*)Xbe + (size_t)N_SZ * D_SZ * 2, 0,
                   (size_t)(NP - N_SZ) * D_SZ * 2, stream);
    conv8<<<dim3((N_SZ * D_SZ / 8 + 255) / 256), 256, 0, stream>>>(ex_feat, Xbe, N_SZ * D_SZ / 8);
  }
  conv8<<<dim3((B_SZ * D_SZ / 8 + 255) / 256), 256, 0, stream>>>(features, fnXb, B_SZ * D_SZ / 8);
  conv8<<<dim3((D_SZ * D_SZ / 8 + 255) / 256), 256, 0, stream>>>(W_g, Wb, D_SZ * D_SZ / 8);

  // grid: id = (y%8) + 8*(x + 6*(y/8)), y in [0,399), x in [0,6)
  proj_gemm2<<<dim3(8 * 6 * 50), 256, 0, stream>>>(fnXb, Xbe, ex_feat, Wb,
                                                   fn8, exfn8, ssqF, ssqE, useA);

  excT_prep<<<dim3(NP / 64), 256, 0, stream>>>(ex_cls, excT8, counts);
  // grid: id = (x%8) + 8*(m + 8*(x/8)), x in [0,49), m in [0,8)
  echo_gemm8<<<dim3(8 * 8 * 7), 256, 0, stream>>>(fn8, exfn8, excT8, ssqF, ssqE, echo);
  finalize<<<dim3(1), 1024, 0, stream>>>(echo, counts, labels, creps, out);
}

// Round 10
// 273.195 us; speedup vs baseline: 1.8742x; 1.1517x over previous
//
#include <hip/hip_runtime.h>

#define D_SZ 768
#define N_SZ 50000
#define L_SZ 28
#define B_SZ 1024
#define NP   50048   // 391 * 128 (padded N)
#define NT   391     // n-tiles of 128

typedef float f32x4 __attribute__((ext_vector_type(4)));
typedef int i32x8 __attribute__((ext_vector_type(8)));

// byte-order-proof single fp8 e4m3 convert (both packed bytes equal)
__device__ __forceinline__ unsigned char f2fp8(float a) {
  unsigned r;
  asm("v_cvt_pk_fp8_f32 %0, %1, %2" : "=v"(r) : "v"(a), "v"(a));
  return (unsigned char)(r & 0xFF);
}
// pack 4 floats -> 4 fp8 bytes (byte i = fp8(arg i), little-endian)
__device__ __forceinline__ unsigned pk4_fp8(float a, float b, float c, float d) {
  unsigned lo, hi;
  asm("v_cvt_pk_fp8_f32 %0, %1, %2" : "=v"(lo) : "v"(a), "v"(b));
  asm("v_cvt_pk_fp8_f32 %0, %1, %2" : "=v"(hi) : "v"(c), "v"(d));
  return (lo & 0xFFFFu) | (hi << 16);
}
__device__ __forceinline__ i32x8 mk8(uint4 lo, uint4 hi) {
  i32x8 r;
  r[0] = (int)lo.x; r[1] = (int)lo.y; r[2] = (int)lo.z; r[3] = (int)lo.w;
  r[4] = (int)hi.x; r[5] = (int)hi.y; r[6] = (int)hi.z; r[7] = (int)hi.w;
  return r;
}
// fp8 e4m3 x fp8 e4m3, K=128, scales = 1.0 (E8M0 0x7F in every byte)
#define MFMA_FP8(a, b, c) \
  __builtin_amdgcn_mfma_scale_f32_16x16x128_f8f6f4((a), (b), (c), 0, 0, \
                                                   0, 0x7F7F7F7F, 0, 0x7F7F7F7F)
#define GLOAD_LDS(g, l) \
  __builtin_amdgcn_global_load_lds((const __attribute__((address_space(1))) void*)(g), \
                                   (__attribute__((address_space(3))) void*)(l), 16, 0, 0)

// ---------------------------------------------------------------------------
// Streaming f32 -> fp8 e4m3 convert (x scale), 8 elems/thread.
// ---------------------------------------------------------------------------
__global__ void convF8(const float* __restrict__ in, unsigned char* __restrict__ out,
                       int n8, float scale)
{
  const int t = blockIdx.x * 256 + threadIdx.x;
  if (t >= n8) return;
  const float4 a0 = *(const float4*)(in + (size_t)t * 8);
  const float4 a1 = *(const float4*)(in + (size_t)t * 8 + 4);
  uint2 o;
  o.x = pk4_fp8(a0.x * scale, a0.y * scale, a0.z * scale, a0.w * scale);
  o.y = pk4_fp8(a1.x * scale, a1.y * scale, a1.z * scale, a1.w * scale);
  *(uint2*)(out + (size_t)t * 8) = o;
}

// ---------------------------------------------------------------------------
// Projection GEMM, fp8 K=128, counted-vmcnt dbuf skeleton (round-9 echo's).
// Y[M][768] fp8 = X8 @ W8^T (W8 pre-scaled x8; scale cancels in cosine).
// Per-row sum-of-squares (f32, scaled) -> global atomics.
// Co-XCD id swizzle: id = (y%8) + 8*(x + 6*(y/8)); y<8 -> features.
// LDS: As/Bs fp8 dbuf 64KB -> 2 blocks/CU.
// ---------------------------------------------------------------------------
__global__ __launch_bounds__(256, 2)
void proj_gemm8(const unsigned char* __restrict__ Xf8,
                const unsigned char* __restrict__ Xe8,
                const unsigned char* __restrict__ W8,
                unsigned char* __restrict__ Yf8, unsigned char* __restrict__ Ye8,
                float* __restrict__ ssqF, float* __restrict__ ssqE)
{
  const int id = blockIdx.x;
  const int slot = id & 7, rest = id >> 3;
  const int x = rest % 6, yq = rest / 6;
  const int y = yq * 8 + slot;
  if (y >= 8 + NT) return;

  __shared__ __align__(16) unsigned char As8[2][128 * 128];
  __shared__ __align__(16) unsigned char Bs8[2][128 * 128];
  const int tid = threadIdx.x;
  const int w = tid >> 6, lane = tid & 63;
  const int wr = w >> 1, wc = w & 1;
  const int fr = lane & 15, fq = lane >> 4;
  const int srow = lane >> 3;                 // 0..7
  const int schunk = (lane & 7) ^ srow;       // pre-swizzled global 16B-chunk
  const int o0 = x * 128;

  const unsigned char* Xb; unsigned char* Y8; float* ssqG; int m0;
  if (y < 8) { Xb = Xf8; Y8 = Yf8; ssqG = ssqF; m0 = y * 128; }
  else       { Xb = Xe8; Y8 = Ye8; ssqG = ssqE; m0 = (y - 8) * 128; }

  auto stage = [&](int buf, int kk) {
#pragma unroll
    for (int i = 0; i < 4; ++i) {
      const int row = w * 32 + i * 8 + srow;
      const unsigned char* ga = Xb + (size_t)(m0 + row) * D_SZ + kk + schunk * 16;
      const unsigned char* gb = W8 + (size_t)(o0 + row) * D_SZ + kk + schunk * 16;
      GLOAD_LDS(ga, &As8[buf][(w * 32 + i * 8) * 128]);
      GLOAD_LDS(gb, &Bs8[buf][(w * 32 + i * 8) * 128]);
    }
  };

  f32x4 acc[4][4] = {};
  int cur = 0;
  stage(0, 0);

  for (int kk = 0; kk < D_SZ; kk += 128) {
    if (kk + 128 < D_SZ) {
      stage(cur ^ 1, kk + 128);
      asm volatile("s_waitcnt vmcnt(8)" ::: "memory");
    } else {
      asm volatile("s_waitcnt vmcnt(0)" ::: "memory");
    }
    __builtin_amdgcn_s_barrier();
    i32x8 af[4], bfv[4];
#pragma unroll
    for (int i = 0; i < 4; ++i) {
      {
        const int row = wr * 64 + i * 16 + fr;
        const int r7 = row & 7;
        const unsigned char* rb = &As8[cur][row * 128];
        const uint4 lo = *(const uint4*)(rb + (((2 * fq + 0) ^ r7) << 4));
        const uint4 hi = *(const uint4*)(rb + (((2 * fq + 1) ^ r7) << 4));
        af[i] = mk8(lo, hi);
      }
      {
        const int row = wc * 64 + i * 16 + fr;
        const int r7 = row & 7;
        const unsigned char* rb = &Bs8[cur][row * 128];
        const uint4 lo = *(const uint4*)(rb + (((2 * fq + 0) ^ r7) << 4));
        const uint4 hi = *(const uint4*)(rb + (((2 * fq + 1) ^ r7) << 4));
        bfv[i] = mk8(lo, hi);
      }
    }
#pragma unroll
    for (int mi = 0; mi < 4; ++mi)
#pragma unroll
      for (int ni = 0; ni < 4; ++ni)
        acc[mi][ni] = MFMA_FP8(af[mi], bfv[ni], acc[mi][ni]);
    asm volatile("s_waitcnt lgkmcnt(0)" ::: "memory");
    __builtin_amdgcn_s_barrier();
    __builtin_amdgcn_sched_barrier(0);
    cur ^= 1;
  }

  float ssq[4][4] = {};
#pragma unroll
  for (int mi = 0; mi < 4; ++mi)
#pragma unroll
    for (int ni = 0; ni < 4; ++ni)
#pragma unroll
      for (int r = 0; r < 4; ++r) {
        const int row = m0 + wr * 64 + mi * 16 + fq * 4 + r;
        const int col = o0 + wc * 64 + ni * 16 + fr;
        const float v = acc[mi][ni][r];
        Y8[(size_t)row * D_SZ + col] = f2fp8(v);
        ssq[mi][r] += v * v;
      }
#pragma unroll
  for (int mi = 0; mi < 4; ++mi)
#pragma unroll
    for (int r = 0; r < 4; ++r) {
      float v = ssq[mi][r];
      v += __shfl_xor(v, 1); v += __shfl_xor(v, 2);
      v += __shfl_xor(v, 4); v += __shfl_xor(v, 8);
      if (fr == 0) atomicAdd(&ssqG[m0 + wr * 64 + mi * 16 + fq * 4 + r], v);
    }
}

// ---------------------------------------------------------------------------
// Build excT fp8 [32][NP] (exact 0x38 = 1.0 / 0x00 = 0.0) + fused counts.
// ---------------------------------------------------------------------------
__global__ void excT_prep(const float* __restrict__ exc, unsigned char* __restrict__ excT8,
                          float* __restrict__ counts)
{
  __shared__ float lds[64][29];
  const int n0 = blockIdx.x * 64;
  const int tid = threadIdx.x;
  for (int i = tid; i < 64 * L_SZ; i += 256) {
    const int n = i / L_SZ, l = i % L_SZ;
    lds[n][l] = (n0 + n < N_SZ) ? exc[(size_t)(n0 + n) * L_SZ + l] : 0.0f;
  }
  __syncthreads();
  if (tid < L_SZ) {
    float c = 0.f;
    for (int n = 0; n < 64; ++n) c += lds[n][tid];
    atomicAdd(&counts[tid], c);
  }
  for (int i = tid; i < 32 * 64; i += 256) {
    const int l = i >> 6, n = i & 63;
    const unsigned char v = (l < L_SZ && lds[n][l] != 0.0f) ? 0x38 : 0x00;
    excT8[(size_t)l * NP + n0 + n] = v;
  }
}

// ---------------------------------------------------------------------------
// Fused s-GEMM, MX-fp8 K=128 (round-9 proven), minus the redundant
// post-phase-2 barrier pair (next-tile K-step barrier already orders Al8).
// ---------------------------------------------------------------------------
__global__ __launch_bounds__(256, 2)
void echo_gemm8(const unsigned char* __restrict__ fn8,
                const unsigned char* __restrict__ exfn8,
                const unsigned char* __restrict__ excT8,
                const float* __restrict__ ssqF,
                const float* __restrict__ ssqE,
                float* __restrict__ echo)
{
  const int id = blockIdx.x;
  const int slot = id & 7, rest = id >> 3;
  const int m = rest & 7, xq = rest >> 3;
  const int x = xq * 8 + slot;
  if (x >= 49) return;
  const int m0 = m * 128;
  const int ntile = (NT - x * 8 < 8) ? (NT - x * 8) : 8;

  __shared__ __align__(16) unsigned char As8[2][128 * 128];
  __shared__ __align__(16) unsigned char Bs8[2][128 * 128];
  __shared__ __align__(16) unsigned char Al8[128 * 128];
  const int tid = threadIdx.x;
  const int w = tid >> 6, lane = tid & 63;
  const int wr = w >> 1, wc = w & 1;
  const int fr = lane & 15, fq = lane >> 4;
  const int srow = lane >> 3;
  const int schunk = (lane & 7) ^ srow;

  auto stage = [&](int buf, int n0s, int kk) {
#pragma unroll
    for (int i = 0; i < 4; ++i) {
      const int row = w * 32 + i * 8 + srow;
      const unsigned char* ga = fn8 + (size_t)(m0 + row) * D_SZ + kk + schunk * 16;
      const unsigned char* gb = exfn8 + (size_t)(n0s + row) * D_SZ + kk + schunk * 16;
      GLOAD_LDS(ga, &As8[buf][(w * 32 + i * 8) * 128]);
      GLOAD_LDS(gb, &Bs8[buf][(w * 32 + i * 8) * 128]);
    }
  };

  float rf[4][4];
#pragma unroll
  for (int mi = 0; mi < 4; ++mi)
#pragma unroll
    for (int r = 0; r < 4; ++r)
      rf[mi][r] = 1.0f / fmaxf(sqrtf(ssqF[m0 + wr * 64 + mi * 16 + fq * 4 + r]), 1e-12f);

  f32x4 acc2[2][2] = {};
  int cur = 0;
  stage(0, x * 8 * 128, 0);

  for (int ti = 0; ti < ntile; ++ti) {
    const int n0 = (x * 8 + ti) * 128;
    f32x4 acc[4][4] = {};
    for (int kk = 0; kk < D_SZ; kk += 128) {
      if (kk + 128 < D_SZ) {
        stage(cur ^ 1, n0, kk + 128);
        asm volatile("s_waitcnt vmcnt(8)" ::: "memory");
      } else {
        asm volatile("s_waitcnt vmcnt(0)" ::: "memory");
      }
      __builtin_amdgcn_s_barrier();
      i32x8 af[4], bfv[4];
#pragma unroll
      for (int i = 0; i < 4; ++i) {
        {
          const int row = wr * 64 + i * 16 + fr;
          const int r7 = row & 7;
          const unsigned char* rb = &As8[cur][row * 128];
          const uint4 lo = *(const uint4*)(rb + (((2 * fq + 0) ^ r7) << 4));
          const uint4 hi = *(const uint4*)(rb + (((2 * fq + 1) ^ r7) << 4));
          af[i] = mk8(lo, hi);
        }
        {
          const int row = wc * 64 + i * 16 + fr;
          const int r7 = row & 7;
          const unsigned char* rb = &Bs8[cur][row * 128];
          const uint4 lo = *(const uint4*)(rb + (((2 * fq + 0) ^ r7) << 4));
          const uint4 hi = *(const uint4*)(rb + (((2 * fq + 1) ^ r7) << 4));
          bfv[i] = mk8(lo, hi);
        }
      }
#pragma unroll
      for (int mi = 0; mi < 4; ++mi)
#pragma unroll
        for (int ni = 0; ni < 4; ++ni)
          acc[mi][ni] = MFMA_FP8(af[mi], bfv[ni], acc[mi][ni]);
      asm volatile("s_waitcnt lgkmcnt(0)" ::: "memory");
      __builtin_amdgcn_s_barrier();
      __builtin_amdgcn_sched_barrier(0);
      cur ^= 1;
    }
    // cube: a = 64 * s^3 as fp8 into swizzled Al8 (slot s holds n-chunk s^(b&7))
    float rne[4];
#pragma unroll
    for (int ni = 0; ni < 4; ++ni)
      rne[ni] = 1.0f / fmaxf(sqrtf(ssqE[n0 + wc * 64 + ni * 16 + fr]), 1e-12f);
#pragma unroll
    for (int mi = 0; mi < 4; ++mi)
#pragma unroll
      for (int ni = 0; ni < 4; ++ni)
#pragma unroll
        for (int r = 0; r < 4; ++r) {
          const int b = wr * 64 + mi * 16 + fq * 4 + r;
          const int n = wc * 64 + ni * 16 + fr;
          const float s = acc[mi][ni][r] * rf[mi][r] * rne[ni];
          const unsigned byte = (unsigned)(b * 128) + ((((unsigned)(n >> 4)) ^ ((unsigned)b & 7u)) << 4) + ((unsigned)n & 15u);
          Al8[byte] = f2fp8(s * s * s * 64.0f);
        }
    asm volatile("s_waitcnt lgkmcnt(0)" ::: "memory");
    __builtin_amdgcn_s_barrier();
    // phase-2: echo[b][cls] += a[b][n] * excT[cls][n], one K=128 MFMA per frag
    {
      i32x8 pa[2], pb[2];
#pragma unroll
      for (int i = 0; i < 2; ++i) {
        const int row = w * 32 + i * 16 + fr;
        const int r7 = row & 7;
        const unsigned char* rb = &Al8[row * 128];
        const uint4 lo = *(const uint4*)(rb + (((2 * fq + 0) ^ r7) << 4));
        const uint4 hi = *(const uint4*)(rb + (((2 * fq + 1) ^ r7) << 4));
        pa[i] = mk8(lo, hi);
        const unsigned char* gp = excT8 + (size_t)(i * 16 + fr) * NP + n0 + fq * 32;
        const uint4 glo = *(const uint4*)gp;
        const uint4 ghi = *(const uint4*)(gp + 16);
        pb[i] = mk8(glo, ghi);
      }
#pragma unroll
      for (int mi = 0; mi < 2; ++mi)
#pragma unroll
        for (int ni = 0; ni < 2; ++ni)
          acc2[mi][ni] = MFMA_FP8(pa[mi], pb[ni], acc2[mi][ni]);
    }
    // NOTE: no lgkm/barrier here — Al8 is next written only after the next
    // tile's full K-loop (>=2 barriers away); As8/Bs8 reuse is protected by
    // the final K-step's lgkmcnt(0)+barrier.
    if (ti + 1 < ntile) stage(cur, n0 + 128, 0);
  }
#pragma unroll
  for (int mi = 0; mi < 2; ++mi)
#pragma unroll
    for (int ni = 0; ni < 2; ++ni)
#pragma unroll
      for (int r = 0; r < 4; ++r) {
        const int b = w * 32 + mi * 16 + fq * 4 + r;
        const int cls = ni * 16 + fr;
        if (cls < L_SZ)
          atomicAdd(&echo[(size_t)(m0 + b) * L_SZ + cls], acc2[mi][ni][r] * (1.0f / 64.0f));
      }
}

// ---------------------------------------------------------------------------
// Finalize: echo/counts -> neg_dists (vs real class_reps) -> BCE loss.
// ---------------------------------------------------------------------------
__global__ __launch_bounds__(1024)
void finalize(const float* __restrict__ echo, const float* __restrict__ counts,
              const float* __restrict__ labels, const float* __restrict__ creps,
              float* __restrict__ out)
{
  __shared__ float C[L_SZ * L_SZ];
  __shared__ float cnt[L_SZ];
  __shared__ float red[16];
  const int tid = threadIdx.x;
  if (tid < L_SZ * L_SZ) C[tid] = creps[tid];
  if (tid >= 896 && tid < 896 + L_SZ) cnt[tid - 896] = counts[tid - 896];
  __syncthreads();
  float e[L_SZ];
#pragma unroll
  for (int l = 0; l < L_SZ; ++l) e[l] = echo[tid * L_SZ + l] / cnt[l];
  float lsum = 0.f;
  for (int j = 0; j < L_SZ; ++j) {
    float d2 = 0.f;
#pragma unroll
    for (int l = 0; l < L_SZ; ++l) { const float df = e[l] - C[j * L_SZ + l]; d2 += df * df; }
    const float nd = -sqrtf(d2);
    out[1 + tid * L_SZ + j] = nd;
    const float y = labels[tid * L_SZ + j];
    const float sp = fmaxf(nd, 0.f) + log1pf(expf(-fabsf(nd)));
    lsum += sp - nd * y;
  }
#pragma unroll
  for (int o = 32; o; o >>= 1) lsum += __shfl_xor(lsum, o);
  if ((tid & 63) == 0) red[tid >> 6] = lsum;
  __syncthreads();
  if (tid < 16) {
    float v = red[tid];
#pragma unroll
    for (int o = 8; o; o >>= 1) v += __shfl_xor(v, o);
    if (tid == 0) out[0] = v * (1.0f / (B_SZ * L_SZ));
  }
}

extern "C" void kernel_launch(void* const* d_in, const int* in_sizes, int n_in,
                              void* d_out, int out_size, void* d_ws, size_t ws_size,
                              hipStream_t stream)
{
  (void)in_sizes; (void)n_in; (void)out_size;
  const float* features = (const float*)d_in[0];
  const float* labels   = (const float*)d_in[1];
  const float* W_g      = (const float*)d_in[2];
  const float* ex_feat  = (const float*)d_in[3];
  const float* ex_cls   = (const float*)d_in[4];
  const float* creps    = (const float*)d_in[5];
  float* out = (float*)d_out;

  const size_t OFF_EXFN8 = 0;                                  // NP*768 = 38,436,864
  const size_t OFF_FN8   = OFF_EXFN8 + (size_t)NP * D_SZ;      // + 786,432
  const size_t OFF_EXCT8 = OFF_FN8 + (size_t)B_SZ * D_SZ;      // + 1,601,536
  const size_t OFF_X8E   = OFF_EXCT8 + (size_t)32 * NP;        // + 38,436,864
  const size_t OFF_X8F   = OFF_X8E + (size_t)NP * D_SZ;        // + 786,432
  const size_t OFF_W8    = OFF_X8F + (size_t)B_SZ * D_SZ;      // + 589,824
  const size_t OFF_ECHO  = OFF_W8 + (size_t)D_SZ * D_SZ;       // + 114,688
  const size_t OFF_SSQE  = OFF_ECHO + (size_t)B_SZ * L_SZ * 4; // + 200,192
  const size_t OFF_SSQF  = OFF_SSQE + (size_t)NP * 4;          // + 4,096
  const size_t OFF_CNT   = OFF_SSQF + (size_t)B_SZ * 4;        // + 128
  const size_t NEED      = OFF_CNT + 128;                      // ~81.0 MB (<= proven >=82 MB)
  if (ws_size < NEED) return;

  char* ws = (char*)d_ws;
  unsigned char* exfn8 = (unsigned char*)(ws + OFF_EXFN8);
  unsigned char* fn8   = (unsigned char*)(ws + OFF_FN8);
  unsigned char* excT8 = (unsigned char*)(ws + OFF_EXCT8);
  unsigned char* X8e   = (unsigned char*)(ws + OFF_X8E);
  unsigned char* X8f   = (unsigned char*)(ws + OFF_X8F);
  unsigned char* W8    = (unsigned char*)(ws + OFF_W8);
  float* echo   = (float*)(ws + OFF_ECHO);
  float* ssqE   = (float*)(ws + OFF_SSQE);
  float* ssqF   = (float*)(ws + OFF_SSQF);
  float* counts = (float*)(ws + OFF_CNT);

  // zero echo + ssqE + ssqF + counts (contiguous span)
  hipMemsetAsync(ws + OFF_ECHO, 0, OFF_CNT + 128 - OFF_ECHO, stream);
  // zero the 48 pad rows of X8e
  hipMemsetAsync(X8e + (size_t)N_SZ * D_SZ, 0, (size_t)(NP - N_SZ) * D_SZ, stream);

  convF8<<<dim3((N_SZ * D_SZ / 8 + 255) / 256), 256, 0, stream>>>(ex_feat, X8e, N_SZ * D_SZ / 8, 1.0f);
  convF8<<<dim3((B_SZ * D_SZ / 8 + 255) / 256), 256, 0, stream>>>(features, X8f, B_SZ * D_SZ / 8, 1.0f);
  convF8<<<dim3((D_SZ * D_SZ / 8 + 255) / 256), 256, 0, stream>>>(W_g, W8, D_SZ * D_SZ / 8, 8.0f);

  // grid: id = (y%8) + 8*(x + 6*(y/8)), y in [0,399), x in [0,6)
  proj_gemm8<<<dim3(8 * 6 * 50), 256, 0, stream>>>(X8f, X8e, W8, fn8, exfn8, ssqF, ssqE);

  excT_prep<<<dim3(NP / 64), 256, 0, stream>>>(ex_cls, excT8, counts);
  // grid: id = (x%8) + 8*(m + 8*(x/8)), x in [0,49), m in [0,8)
  echo_gemm8<<<dim3(8 * 8 * 7), 256, 0, stream>>>(fn8, exfn8, excT8, ssqF, ssqE, echo);
  finalize<<<dim3(1), 1024, 0, stream>>>(echo, counts, labels, creps, out);
}